// Round 3
// baseline (33338.565 us; speedup 1.0000x reference)
//
#include <hip/hip_runtime.h>
#include <hip/hip_bf16.h>
#include <math.h>

#define B_  64
#define S_  256
#define D_  1024
#define H_  1024
#define E_  128
#define O_  512
#define IN_ 1152   // D + E
#define G4_ 4096   // 4*H
#define KU_ 1152   // E + H   (u = [emb(128) | h(1024)])
#define KW_ 144    // per-wave K chunk in gates (8 waves * 144 = 1152)

// ws layout (floats):
//   u_g : [4 bgrp][1152 k][16 b]   (emb rows 0..127, h rows 128..1151)
//   c_g : [1024 jj][64 b]
//   lp  : [64 b][64 jc][512 o]
//   bar : 64 floats reserved (unsigned barrier counter at [0])
//   xwb : [CH*64 rows][4096]

// ---------------- inline grid barrier (NO function call -> no spill around it) ----------------
__device__ __forceinline__ void gridbar(unsigned* bar, unsigned target) {
  __syncthreads();
  if (threadIdx.x == 0) {
    __threadfence();   // release: make this block's prior writes agent-visible
    __hip_atomic_fetch_add(bar, 1u, __ATOMIC_RELAXED, __HIP_MEMORY_SCOPE_AGENT);
    while (__hip_atomic_load(bar, __ATOMIC_RELAXED, __HIP_MEMORY_SCOPE_AGENT) < target) {
      __builtin_amdgcn_s_sleep(2);
    }
    __threadfence();   // acquire: invalidate stale lines before block proceeds
  }
  __syncthreads();
}

// ---------------- init: u (emb=init_tensor, h=0), c=0, bar=0 ----------------
__global__ __launch_bounds__(256) void k_init(
    const float* __restrict__ init_tensor,
    float* __restrict__ u_g, float* __restrict__ c_g,
    unsigned* __restrict__ bar)
{
  if (blockIdx.x == 0 && threadIdx.x == 0) *bar = 0u;
  const int NU = 4 * KU_ * 16;   // 73728
  const int NC = H_ * B_;        // 65536
  for (int idx = blockIdx.x * 256 + threadIdx.x; idx < NU + NC; idx += gridDim.x * 256) {
    if (idx < NU) {
      int k = (idx >> 4) % KU_;
      u_g[idx] = (k < E_) ? init_tensor[k] : 0.f;
    } else {
      c_g[idx - NU] = 0.f;
    }
  }
}

// ---------------- precompute xwb[t,b][j] = x_t[b] @ w_ih[:, :1024]^T + (b_ih+b_hh) ----------------
__global__ __launch_bounds__(256) void k_xw(
    const float* __restrict__ hidden,
    const float* __restrict__ w_ih,
    const float* __restrict__ b_ih,
    const float* __restrict__ b_hh,
    float* __restrict__ xwb, int t0, int rows)
{
  __shared__ float a_t[16][132];
  __shared__ float b_t[16][132];
  const int tid = threadIdx.x;
  const int tx = tid & 15, ty = tid >> 4;
  const int m_base = blockIdx.x * 128;
  const int n_base = blockIdx.y * 128;
  float acc[8][8];
#pragma unroll
  for (int i = 0; i < 8; ++i)
#pragma unroll
    for (int j = 0; j < 8; ++j) acc[i][j] = 0.f;

  for (int k0 = 0; k0 < D_; k0 += 16) {
#pragma unroll
    for (int l = 0; l < 2; ++l) {
      int s = tid + l * 256;
      int r = s >> 2, kq = (s & 3) << 2;
      int m = m_base + r;
      float4 v = make_float4(0.f, 0.f, 0.f, 0.f);
      if (m < rows) {
        int t = t0 + (m >> 6), b = m & 63;
        v = *(const float4*)(hidden + ((size_t)b * S_ + t) * D_ + k0 + kq);
      }
      a_t[kq + 0][r] = v.x; a_t[kq + 1][r] = v.y; a_t[kq + 2][r] = v.z; a_t[kq + 3][r] = v.w;
      int j = n_base + r;
      float4 w = *(const float4*)(w_ih + (size_t)j * IN_ + k0 + kq);
      b_t[kq + 0][r] = w.x; b_t[kq + 1][r] = w.y; b_t[kq + 2][r] = w.z; b_t[kq + 3][r] = w.w;
    }
    __syncthreads();
#pragma unroll
    for (int k = 0; k < 16; ++k) {
      float av[8], bv[8];
      *(float4*)&av[0] = *(const float4*)&a_t[k][ty * 4];
      *(float4*)&av[4] = *(const float4*)&a_t[k][64 + ty * 4];
      *(float4*)&bv[0] = *(const float4*)&b_t[k][tx * 4];
      *(float4*)&bv[4] = *(const float4*)&b_t[k][64 + tx * 4];
#pragma unroll
      for (int i = 0; i < 8; ++i)
#pragma unroll
        for (int j = 0; j < 8; ++j)
          acc[i][j] = fmaf(av[i], bv[j], acc[i][j]);
    }
    __syncthreads();
  }
  float bias[8];
#pragma unroll
  for (int cj = 0; cj < 8; ++cj) {
    int col = n_base + ((cj < 4) ? (tx * 4 + cj) : (64 + tx * 4 + cj - 4));
    bias[cj] = b_ih[col] + b_hh[col];
  }
#pragma unroll
  for (int ri = 0; ri < 8; ++ri) {
    int m = m_base + ((ri < 4) ? (ty * 4 + ri) : (64 + ty * 4 + ri - 4));
    if (m < rows) {
      float4 s0 = make_float4(acc[ri][0] + bias[0], acc[ri][1] + bias[1],
                              acc[ri][2] + bias[2], acc[ri][3] + bias[3]);
      float4 s1 = make_float4(acc[ri][4] + bias[4], acc[ri][5] + bias[5],
                              acc[ri][6] + bias[6], acc[ri][7] + bias[7]);
      *(float4*)(xwb + (size_t)m * G4_ + n_base + tx * 4) = s0;
      *(float4*)(xwb + (size_t)m * G4_ + n_base + 64 + tx * 4) = s1;
    }
  }
}

// ---------------- persistent stepper (manual grid barrier, weights in VGPRs) ----------------
// grid 256 = (jc 0..63) * 4 + (bgrp 0..3); block 512 = 8 waves.
// lane: g = lane>>4 (gate i,f,g,o), jjl = lane&15 -> j = g*1024 + jc*16 + jjl
// wave ks: K chunk [ks*144, +144) of u = [emb(128)|h(1024)]
__global__ __launch_bounds__(512, 2) void k_steps(
    const float* __restrict__ w_ih, const float* __restrict__ w_hh,
    const float* __restrict__ w_out, const float* __restrict__ b_out,
    const float* __restrict__ emb_table, const int* __restrict__ seq_lens,
    const float* __restrict__ xwb,
    float* __restrict__ u_g, float* __restrict__ c_g, float* __restrict__ lp,
    float* __restrict__ out, unsigned* __restrict__ bar, unsigned bar_base,
    int t0, int nsteps)
{
  __shared__ float u_lds[KU_ * 16];     // [k][16b] 73728 B
  __shared__ float red[8 * 64 * 20];    // [wave][lane][16b pad20] 40960 B
  __shared__ float h_lds[16 * 16];      // [k-local][16b]

  const int bid  = blockIdx.x;
  const int jc   = bid >> 2;
  const int bgrp = bid & 3;
  const int tid  = threadIdx.x;
  const int wave = tid >> 6;
  const int lane = tid & 63;
  const int g    = lane >> 4;
  const int jjl  = lane & 15;
  const int j    = g * H_ + jc * 16 + jjl;

  // persistent per-lane weights: gates (144) + logits (16)
  float wg[KW_];
  {
    const int kbase = wave * KW_;
#pragma unroll
    for (int k = 0; k < KW_; ++k) {
      int kg = kbase + k;
      wg[k] = (kg < E_) ? w_ih[(size_t)j * IN_ + D_ + kg]
                        : w_hh[(size_t)j * H_ + (kg - E_)];
    }
  }
  float wo[16];
#pragma unroll
  for (int k = 0; k < 16; ++k)
    wo[k] = w_out[(size_t)tid * H_ + jc * 16 + k];

  float* u_my = u_g + (size_t)bgrp * KU_ * 16;

  unsigned tgt = bar_base + 256u;

  for (int tt = 0; tt < nsteps; ++tt) {
    const int t = t0 + tt;

    // ---- stage this bgrp's u slice -> LDS (contiguous, coalesced)
    for (int i = tid; i < KU_ * 4; i += 512)
      *(float4*)&u_lds[i * 4] = *(const float4*)&u_my[i * 4];
    __syncthreads();

    // ---- phase A: gates partial over this wave's K chunk (u broadcast from LDS)
    float acc[16];
#pragma unroll
    for (int b = 0; b < 16; ++b) acc[b] = 0.f;
    {
      const float* up = u_lds + wave * KW_ * 16;
#pragma unroll
      for (int k = 0; k < KW_; ++k) {
        float4 u0 = *(const float4*)(up + k * 16 + 0);
        float4 u1 = *(const float4*)(up + k * 16 + 4);
        float4 u2 = *(const float4*)(up + k * 16 + 8);
        float4 u3 = *(const float4*)(up + k * 16 + 12);
        float wk = wg[k];
        acc[0]  = fmaf(wk, u0.x, acc[0]);  acc[1]  = fmaf(wk, u0.y, acc[1]);
        acc[2]  = fmaf(wk, u0.z, acc[2]);  acc[3]  = fmaf(wk, u0.w, acc[3]);
        acc[4]  = fmaf(wk, u1.x, acc[4]);  acc[5]  = fmaf(wk, u1.y, acc[5]);
        acc[6]  = fmaf(wk, u1.z, acc[6]);  acc[7]  = fmaf(wk, u1.w, acc[7]);
        acc[8]  = fmaf(wk, u2.x, acc[8]);  acc[9]  = fmaf(wk, u2.y, acc[9]);
        acc[10] = fmaf(wk, u2.z, acc[10]); acc[11] = fmaf(wk, u2.w, acc[11]);
        acc[12] = fmaf(wk, u3.x, acc[12]); acc[13] = fmaf(wk, u3.y, acc[13]);
        acc[14] = fmaf(wk, u3.z, acc[14]); acc[15] = fmaf(wk, u3.w, acc[15]);
      }
    }
    {
      float* rp = &red[(wave * 64 + lane) * 20];
#pragma unroll
      for (int q = 0; q < 4; ++q)
        *(float4*)&rp[q * 4] = make_float4(acc[q * 4], acc[q * 4 + 1],
                                           acc[q * 4 + 2], acc[q * 4 + 3]);
    }
    __syncthreads();

    // ---- phase B: K-reduce + LSTM cell (threads 0..255), block-local
    if (tid < 256) {
      const int jl = tid & 15, bb = tid >> 4;
      const int b = bgrp * 16 + bb;
      const int jjg = jc * 16 + jl;
      float gv[4];
#pragma unroll
      for (int gg = 0; gg < 4; ++gg) {
        float s = xwb[((size_t)tt * B_ + b) * G4_ + gg * H_ + jjg];
#pragma unroll
        for (int w = 0; w < 8; ++w)
          s += red[(w * 64 + gg * 16 + jl) * 20 + bb];
        gv[gg] = s;
      }
      float iv = 1.f / (1.f + expf(-gv[0]));
      float fv = 1.f / (1.f + expf(-gv[1]));
      float gg2 = tanhf(gv[2]);
      float ov = 1.f / (1.f + expf(-gv[3]));
      float cc = fv * c_g[(size_t)jjg * B_ + b] + iv * gg2;
      c_g[(size_t)jjg * B_ + b] = cc;
      float hv = ov * tanhf(cc);
      u_my[(size_t)(E_ + jjg) * 16 + bb] = hv;   // h row of this bgrp's u slice
      h_lds[jl * 16 + bb] = hv;
    }
    __syncthreads();

    // ---- phase C: logits partial over this block's 16-k h slice; o = tid
    {
      float acc2[16];
#pragma unroll
      for (int b = 0; b < 16; ++b) acc2[b] = 0.f;
#pragma unroll
      for (int k = 0; k < 16; ++k) {
        float4 h0 = *(const float4*)&h_lds[k * 16 + 0];
        float4 h1 = *(const float4*)&h_lds[k * 16 + 4];
        float4 h2 = *(const float4*)&h_lds[k * 16 + 8];
        float4 h3 = *(const float4*)&h_lds[k * 16 + 12];
        float wk = wo[k];
        acc2[0]  = fmaf(wk, h0.x, acc2[0]);  acc2[1]  = fmaf(wk, h0.y, acc2[1]);
        acc2[2]  = fmaf(wk, h0.z, acc2[2]);  acc2[3]  = fmaf(wk, h0.w, acc2[3]);
        acc2[4]  = fmaf(wk, h1.x, acc2[4]);  acc2[5]  = fmaf(wk, h1.y, acc2[5]);
        acc2[6]  = fmaf(wk, h1.z, acc2[6]);  acc2[7]  = fmaf(wk, h1.w, acc2[7]);
        acc2[8]  = fmaf(wk, h2.x, acc2[8]);  acc2[9]  = fmaf(wk, h2.y, acc2[9]);
        acc2[10] = fmaf(wk, h2.z, acc2[10]); acc2[11] = fmaf(wk, h2.w, acc2[11]);
        acc2[12] = fmaf(wk, h3.x, acc2[12]); acc2[13] = fmaf(wk, h3.y, acc2[13]);
        acc2[14] = fmaf(wk, h3.z, acc2[14]); acc2[15] = fmaf(wk, h3.w, acc2[15]);
      }
#pragma unroll
      for (int bb = 0; bb < 16; ++bb)
        lp[(((size_t)(bgrp * 16 + bb)) * 64 + jc) * O_ + tid] = acc2[bb];
    }
    gridbar(bar, tgt); tgt += 256u;

    // ---- phase D: blocks 0..63 (b = bid): reduce logits, store, argmax, emb feedback
    if (bid < B_) {
      const int b = bid;
      float v = b_out[tid];
      const float* lpb = lp + (size_t)b * 64 * O_;
#pragma unroll 8
      for (int q = 0; q < 64; ++q) v += lpb[(size_t)q * O_ + tid];
      int len = seq_lens[b];
      out[((size_t)b * S_ + t) * O_ + tid] = (t < len) ? v : 0.f;
      float* sv = red;
      int*   si = (int*)(red + 512);
      sv[tid] = v; si[tid] = tid;
      __syncthreads();
      for (int s = 256; s > 0; s >>= 1) {
        if (tid < s) {
          float ov2 = sv[tid + s]; int oi = si[tid + s];
          if (ov2 > sv[tid] || (ov2 == sv[tid] && oi < si[tid])) { sv[tid] = ov2; si[tid] = oi; }
        }
        __syncthreads();
      }
      int idx = si[0];
      if (tid < E_)
        u_g[(size_t)(b >> 4) * KU_ * 16 + (size_t)tid * 16 + (b & 15)] =
            emb_table[(size_t)idx * E_ + tid];
    }
    gridbar(bar, tgt); tgt += 256u;
  }
}

extern "C" void kernel_launch(void* const* d_in, const int* in_sizes, int n_in,
                              void* d_out, int out_size, void* d_ws, size_t ws_size,
                              hipStream_t stream) {
  const float* hidden      = (const float*)d_in[0];
  const float* init_tensor = (const float*)d_in[1];
  const float* emb_table   = (const float*)d_in[2];
  const float* w_ih        = (const float*)d_in[3];
  const float* w_hh        = (const float*)d_in[4];
  const float* b_ih        = (const float*)d_in[5];
  const float* b_hh        = (const float*)d_in[6];
  const float* w_out       = (const float*)d_in[7];
  const float* b_out       = (const float*)d_in[8];
  const int*   seq_lens    = (const int*)d_in[9];
  float* out = (float*)d_out;
  float* ws  = (float*)d_ws;

  const size_t U_OFF  = 0;
  const size_t C_OFF  = U_OFF + (size_t)4 * KU_ * 16;      // 73728
  const size_t LP_OFF = C_OFF + (size_t)H_ * B_;           // +65536
  const size_t BAR_OFF= LP_OFF + (size_t)B_ * 64 * O_;     // +2097152
  const size_t XW_OFF = BAR_OFF + 64;                      // (~8.9 MB fixed)

  long long avail = (long long)(ws_size / 4) - (long long)XW_OFF;
  long long chl = avail / ((long long)B_ * G4_);
  int CH = (int)(chl < 1 ? 1 : (chl > S_ ? S_ : chl));

  unsigned* bar = (unsigned*)(ws + BAR_OFF);

  k_init<<<dim3(544), dim3(256), 0, stream>>>(init_tensor, ws + U_OFF, ws + C_OFF, bar);

  unsigned bar_base = 0;
  for (int t0 = 0; t0 < S_; t0 += CH) {
    int ch = (S_ - t0 < CH) ? (S_ - t0) : CH;
    int rows = ch * B_;
    dim3 pg((rows + 127) / 128, G4_ / 128);
    k_xw<<<pg, dim3(256), 0, stream>>>(hidden, w_ih, b_ih, b_hh, ws + XW_OFF, t0, rows);

    const float* xwbp = ws + XW_OFF;
    float* u_p  = ws + U_OFF;
    float* c_p  = ws + C_OFF;
    float* lp_p = ws + LP_OFF;
    int t0v = t0, nst = ch;
    void* args[] = { (void*)&w_ih, (void*)&w_hh, (void*)&w_out, (void*)&b_out,
                     (void*)&emb_table, (void*)&seq_lens, (void*)&xwbp,
                     (void*)&u_p, (void*)&c_p, (void*)&lp_p, (void*)&out,
                     (void*)&bar, (void*)&bar_base, (void*)&t0v, (void*)&nst };
    hipLaunchCooperativeKernel((void*)k_steps, dim3(256), dim3(512), args, 0, stream);
    bar_base += (unsigned)(2 * ch) * 256u;
  }
}

// Round 4
// 32443.683 us; speedup vs baseline: 1.0276x; 1.0276x over previous
//
#include <hip/hip_runtime.h>
#include <hip/hip_bf16.h>
#include <math.h>

#define B_  64
#define S_  256
#define D_  1024
#define H_  1024
#define E_  128
#define O_  512
#define IN_ 1152   // D + E
#define G4_ 4096   // 4*H
#define KU_ 1152   // E + H   (u = [emb(128) | h(1024)])
#define KW_ 144    // per-wave K chunk in gates (8 waves * 144 = 1152)

// ws layout (floats):
//   u_g : [4 bgrp][1152 k][16 b]   (emb rows 0..127, h rows 128..1151)
//   c_g : [1024 jj][64 b]
//   lp  : [64 b][64 jc][512 o]
//   bar : 64 floats reserved (unsigned barrier counter at [0])
//   xwb : [CH*64 rows][4096]

// ---------------- inline grid barrier (NO function call -> no spill around it) ----------------
__device__ __forceinline__ void gridbar(unsigned* bar, unsigned target) {
  __syncthreads();
  if (threadIdx.x == 0) {
    __threadfence();   // release: make this block's prior writes agent-visible
    __hip_atomic_fetch_add(bar, 1u, __ATOMIC_RELAXED, __HIP_MEMORY_SCOPE_AGENT);
    while (__hip_atomic_load(bar, __ATOMIC_RELAXED, __HIP_MEMORY_SCOPE_AGENT) < target) {
      __builtin_amdgcn_s_sleep(2);
    }
    __threadfence();   // acquire: invalidate stale lines before block proceeds
  }
  __syncthreads();
}

// ---------------- init: u (emb=init_tensor, h=0), c=0, bar=0 ----------------
__global__ __launch_bounds__(256) void k_init(
    const float* __restrict__ init_tensor,
    float* __restrict__ u_g, float* __restrict__ c_g,
    unsigned* __restrict__ bar)
{
  if (blockIdx.x == 0 && threadIdx.x == 0) *bar = 0u;
  const int NU = 4 * KU_ * 16;   // 73728
  const int NC = H_ * B_;        // 65536
  for (int idx = blockIdx.x * 256 + threadIdx.x; idx < NU + NC; idx += gridDim.x * 256) {
    if (idx < NU) {
      int k = (idx >> 4) % KU_;
      u_g[idx] = (k < E_) ? init_tensor[k] : 0.f;
    } else {
      c_g[idx - NU] = 0.f;
    }
  }
}

// ---------------- precompute xwb[t,b][j] = x_t[b] @ w_ih[:, :1024]^T + (b_ih+b_hh) ----------------
__global__ __launch_bounds__(256) void k_xw(
    const float* __restrict__ hidden,
    const float* __restrict__ w_ih,
    const float* __restrict__ b_ih,
    const float* __restrict__ b_hh,
    float* __restrict__ xwb, int t0, int rows)
{
  __shared__ float a_t[16][132];
  __shared__ float b_t[16][132];
  const int tid = threadIdx.x;
  const int tx = tid & 15, ty = tid >> 4;
  const int m_base = blockIdx.x * 128;
  const int n_base = blockIdx.y * 128;
  float acc[8][8];
#pragma unroll
  for (int i = 0; i < 8; ++i)
#pragma unroll
    for (int j = 0; j < 8; ++j) acc[i][j] = 0.f;

  for (int k0 = 0; k0 < D_; k0 += 16) {
#pragma unroll
    for (int l = 0; l < 2; ++l) {
      int s = tid + l * 256;
      int r = s >> 2, kq = (s & 3) << 2;
      int m = m_base + r;
      float4 v = make_float4(0.f, 0.f, 0.f, 0.f);
      if (m < rows) {
        int t = t0 + (m >> 6), b = m & 63;
        v = *(const float4*)(hidden + ((size_t)b * S_ + t) * D_ + k0 + kq);
      }
      a_t[kq + 0][r] = v.x; a_t[kq + 1][r] = v.y; a_t[kq + 2][r] = v.z; a_t[kq + 3][r] = v.w;
      int j = n_base + r;
      float4 w = *(const float4*)(w_ih + (size_t)j * IN_ + k0 + kq);
      b_t[kq + 0][r] = w.x; b_t[kq + 1][r] = w.y; b_t[kq + 2][r] = w.z; b_t[kq + 3][r] = w.w;
    }
    __syncthreads();
#pragma unroll
    for (int k = 0; k < 16; ++k) {
      float av[8], bv[8];
      *(float4*)&av[0] = *(const float4*)&a_t[k][ty * 4];
      *(float4*)&av[4] = *(const float4*)&a_t[k][64 + ty * 4];
      *(float4*)&bv[0] = *(const float4*)&b_t[k][tx * 4];
      *(float4*)&bv[4] = *(const float4*)&b_t[k][64 + tx * 4];
#pragma unroll
      for (int i = 0; i < 8; ++i)
#pragma unroll
        for (int j = 0; j < 8; ++j)
          acc[i][j] = fmaf(av[i], bv[j], acc[i][j]);
    }
    __syncthreads();
  }
  float bias[8];
#pragma unroll
  for (int cj = 0; cj < 8; ++cj) {
    int col = n_base + ((cj < 4) ? (tx * 4 + cj) : (64 + tx * 4 + cj - 4));
    bias[cj] = b_ih[col] + b_hh[col];
  }
#pragma unroll
  for (int ri = 0; ri < 8; ++ri) {
    int m = m_base + ((ri < 4) ? (ty * 4 + ri) : (64 + ty * 4 + ri - 4));
    if (m < rows) {
      float4 s0 = make_float4(acc[ri][0] + bias[0], acc[ri][1] + bias[1],
                              acc[ri][2] + bias[2], acc[ri][3] + bias[3]);
      float4 s1 = make_float4(acc[ri][4] + bias[4], acc[ri][5] + bias[5],
                              acc[ri][6] + bias[6], acc[ri][7] + bias[7]);
      *(float4*)(xwb + (size_t)m * G4_ + n_base + tx * 4) = s0;
      *(float4*)(xwb + (size_t)m * G4_ + n_base + 64 + tx * 4) = s1;
    }
  }
}

// ---------------- persistent stepper (manual grid barrier, weights in VGPRs) ----------------
// grid 256 = (jc 0..63) * 4 + (bgrp 0..3); block 512 = 8 waves.
// lane: g = lane>>4 (gate i,f,g,o), jjl = lane&15 -> j = g*1024 + jc*16 + jjl
// wave ks: K chunk [ks*144, +144) of u = [emb(128)|h(1024)]
// __launch_bounds__(512, 1): ONLY schedulability cap (2 waves/SIMD -> 256 VGPR).
// (512, 2) capped the allocator at 128 VGPR and spilled wg[144] -> 30 GB scratch reads.
__global__ __launch_bounds__(512, 1) void k_steps(
    const float* __restrict__ w_ih, const float* __restrict__ w_hh,
    const float* __restrict__ w_out, const float* __restrict__ b_out,
    const float* __restrict__ emb_table, const int* __restrict__ seq_lens,
    const float* __restrict__ xwb,
    float* __restrict__ u_g, float* __restrict__ c_g, float* __restrict__ lp,
    float* __restrict__ out, unsigned* __restrict__ bar, unsigned bar_base,
    int t0, int nsteps)
{
  __shared__ float u_lds[KU_ * 16];     // [k][16b] 73728 B
  __shared__ float red[8 * 64 * 20];    // [wave][lane][16b pad20] 40960 B
  __shared__ float h_lds[16 * 16];      // [k-local][16b]

  const int bid  = blockIdx.x;
  const int jc   = bid >> 2;
  const int bgrp = bid & 3;
  const int tid  = threadIdx.x;
  const int wave = tid >> 6;
  const int lane = tid & 63;
  const int g    = lane >> 4;
  const int jjl  = lane & 15;
  const int j    = g * H_ + jc * 16 + jjl;

  // persistent per-lane weights: gates (144) + logits (16)
  float wg[KW_];
  {
    const int kbase = wave * KW_;
#pragma unroll
    for (int k = 0; k < KW_; ++k) {
      int kg = kbase + k;
      wg[k] = (kg < E_) ? w_ih[(size_t)j * IN_ + D_ + kg]
                        : w_hh[(size_t)j * H_ + (kg - E_)];
    }
  }
  float wo[16];
#pragma unroll
  for (int k = 0; k < 16; ++k)
    wo[k] = w_out[(size_t)tid * H_ + jc * 16 + k];

  float* u_my = u_g + (size_t)bgrp * KU_ * 16;

  unsigned tgt = bar_base + 256u;

  for (int tt = 0; tt < nsteps; ++tt) {
    const int t = t0 + tt;

    // ---- stage this bgrp's u slice -> LDS (contiguous, coalesced)
    for (int i = tid; i < KU_ * 4; i += 512)
      *(float4*)&u_lds[i * 4] = *(const float4*)&u_my[i * 4];
    __syncthreads();

    // ---- phase A: gates partial over this wave's K chunk (u broadcast from LDS)
    float acc[16];
#pragma unroll
    for (int b = 0; b < 16; ++b) acc[b] = 0.f;
    {
      const float* up = u_lds + wave * KW_ * 16;
#pragma unroll
      for (int k = 0; k < KW_; ++k) {
        float4 u0 = *(const float4*)(up + k * 16 + 0);
        float4 u1 = *(const float4*)(up + k * 16 + 4);
        float4 u2 = *(const float4*)(up + k * 16 + 8);
        float4 u3 = *(const float4*)(up + k * 16 + 12);
        float wk = wg[k];
        acc[0]  = fmaf(wk, u0.x, acc[0]);  acc[1]  = fmaf(wk, u0.y, acc[1]);
        acc[2]  = fmaf(wk, u0.z, acc[2]);  acc[3]  = fmaf(wk, u0.w, acc[3]);
        acc[4]  = fmaf(wk, u1.x, acc[4]);  acc[5]  = fmaf(wk, u1.y, acc[5]);
        acc[6]  = fmaf(wk, u1.z, acc[6]);  acc[7]  = fmaf(wk, u1.w, acc[7]);
        acc[8]  = fmaf(wk, u2.x, acc[8]);  acc[9]  = fmaf(wk, u2.y, acc[9]);
        acc[10] = fmaf(wk, u2.z, acc[10]); acc[11] = fmaf(wk, u2.w, acc[11]);
        acc[12] = fmaf(wk, u3.x, acc[12]); acc[13] = fmaf(wk, u3.y, acc[13]);
        acc[14] = fmaf(wk, u3.z, acc[14]); acc[15] = fmaf(wk, u3.w, acc[15]);
      }
    }
    {
      float* rp = &red[(wave * 64 + lane) * 20];
#pragma unroll
      for (int q = 0; q < 4; ++q)
        *(float4*)&rp[q * 4] = make_float4(acc[q * 4], acc[q * 4 + 1],
                                           acc[q * 4 + 2], acc[q * 4 + 3]);
    }
    __syncthreads();

    // ---- phase B: K-reduce + LSTM cell (threads 0..255), block-local
    if (tid < 256) {
      const int jl = tid & 15, bb = tid >> 4;
      const int b = bgrp * 16 + bb;
      const int jjg = jc * 16 + jl;
      float gv[4];
#pragma unroll
      for (int gg = 0; gg < 4; ++gg) {
        float s = xwb[((size_t)tt * B_ + b) * G4_ + gg * H_ + jjg];
#pragma unroll
        for (int w = 0; w < 8; ++w)
          s += red[(w * 64 + gg * 16 + jl) * 20 + bb];
        gv[gg] = s;
      }
      float iv = 1.f / (1.f + expf(-gv[0]));
      float fv = 1.f / (1.f + expf(-gv[1]));
      float gg2 = tanhf(gv[2]);
      float ov = 1.f / (1.f + expf(-gv[3]));
      float cc = fv * c_g[(size_t)jjg * B_ + b] + iv * gg2;
      c_g[(size_t)jjg * B_ + b] = cc;
      float hv = ov * tanhf(cc);
      u_my[(size_t)(E_ + jjg) * 16 + bb] = hv;   // h row of this bgrp's u slice
      h_lds[jl * 16 + bb] = hv;
    }
    __syncthreads();

    // ---- phase C: logits partial over this block's 16-k h slice; o = tid
    {
      float acc2[16];
#pragma unroll
      for (int b = 0; b < 16; ++b) acc2[b] = 0.f;
#pragma unroll
      for (int k = 0; k < 16; ++k) {
        float4 h0 = *(const float4*)&h_lds[k * 16 + 0];
        float4 h1 = *(const float4*)&h_lds[k * 16 + 4];
        float4 h2 = *(const float4*)&h_lds[k * 16 + 8];
        float4 h3 = *(const float4*)&h_lds[k * 16 + 12];
        float wk = wo[k];
        acc2[0]  = fmaf(wk, h0.x, acc2[0]);  acc2[1]  = fmaf(wk, h0.y, acc2[1]);
        acc2[2]  = fmaf(wk, h0.z, acc2[2]);  acc2[3]  = fmaf(wk, h0.w, acc2[3]);
        acc2[4]  = fmaf(wk, h1.x, acc2[4]);  acc2[5]  = fmaf(wk, h1.y, acc2[5]);
        acc2[6]  = fmaf(wk, h1.z, acc2[6]);  acc2[7]  = fmaf(wk, h1.w, acc2[7]);
        acc2[8]  = fmaf(wk, h2.x, acc2[8]);  acc2[9]  = fmaf(wk, h2.y, acc2[9]);
        acc2[10] = fmaf(wk, h2.z, acc2[10]); acc2[11] = fmaf(wk, h2.w, acc2[11]);
        acc2[12] = fmaf(wk, h3.x, acc2[12]); acc2[13] = fmaf(wk, h3.y, acc2[13]);
        acc2[14] = fmaf(wk, h3.z, acc2[14]); acc2[15] = fmaf(wk, h3.w, acc2[15]);
      }
#pragma unroll
      for (int bb = 0; bb < 16; ++bb)
        lp[(((size_t)(bgrp * 16 + bb)) * 64 + jc) * O_ + tid] = acc2[bb];
    }
    gridbar(bar, tgt); tgt += 256u;

    // ---- phase D: blocks 0..63 (b = bid): reduce logits, store, argmax, emb feedback
    if (bid < B_) {
      const int b = bid;
      float v = b_out[tid];
      const float* lpb = lp + (size_t)b * 64 * O_;
#pragma unroll 8
      for (int q = 0; q < 64; ++q) v += lpb[(size_t)q * O_ + tid];
      int len = seq_lens[b];
      out[((size_t)b * S_ + t) * O_ + tid] = (t < len) ? v : 0.f;
      float* sv = red;
      int*   si = (int*)(red + 512);
      sv[tid] = v; si[tid] = tid;
      __syncthreads();
      for (int s = 256; s > 0; s >>= 1) {
        if (tid < s) {
          float ov2 = sv[tid + s]; int oi = si[tid + s];
          if (ov2 > sv[tid] || (ov2 == sv[tid] && oi < si[tid])) { sv[tid] = ov2; si[tid] = oi; }
        }
        __syncthreads();
      }
      int idx = si[0];
      if (tid < E_)
        u_g[(size_t)(b >> 4) * KU_ * 16 + (size_t)tid * 16 + (b & 15)] =
            emb_table[(size_t)idx * E_ + tid];
    }
    gridbar(bar, tgt); tgt += 256u;
  }
}

extern "C" void kernel_launch(void* const* d_in, const int* in_sizes, int n_in,
                              void* d_out, int out_size, void* d_ws, size_t ws_size,
                              hipStream_t stream) {
  const float* hidden      = (const float*)d_in[0];
  const float* init_tensor = (const float*)d_in[1];
  const float* emb_table   = (const float*)d_in[2];
  const float* w_ih        = (const float*)d_in[3];
  const float* w_hh        = (const float*)d_in[4];
  const float* b_ih        = (const float*)d_in[5];
  const float* b_hh        = (const float*)d_in[6];
  const float* w_out       = (const float*)d_in[7];
  const float* b_out       = (const float*)d_in[8];
  const int*   seq_lens    = (const int*)d_in[9];
  float* out = (float*)d_out;
  float* ws  = (float*)d_ws;

  const size_t U_OFF  = 0;
  const size_t C_OFF  = U_OFF + (size_t)4 * KU_ * 16;      // 73728
  const size_t LP_OFF = C_OFF + (size_t)H_ * B_;           // +65536
  const size_t BAR_OFF= LP_OFF + (size_t)B_ * 64 * O_;     // +2097152
  const size_t XW_OFF = BAR_OFF + 64;                      // (~8.9 MB fixed)

  long long avail = (long long)(ws_size / 4) - (long long)XW_OFF;
  long long chl = avail / ((long long)B_ * G4_);
  int CH = (int)(chl < 1 ? 1 : (chl > S_ ? S_ : chl));

  unsigned* bar = (unsigned*)(ws + BAR_OFF);

  k_init<<<dim3(544), dim3(256), 0, stream>>>(init_tensor, ws + U_OFF, ws + C_OFF, bar);

  unsigned bar_base = 0;
  for (int t0 = 0; t0 < S_; t0 += CH) {
    int ch = (S_ - t0 < CH) ? (S_ - t0) : CH;
    int rows = ch * B_;
    dim3 pg((rows + 127) / 128, G4_ / 128);
    k_xw<<<pg, dim3(256), 0, stream>>>(hidden, w_ih, b_ih, b_hh, ws + XW_OFF, t0, rows);

    const float* xwbp = ws + XW_OFF;
    float* u_p  = ws + U_OFF;
    float* c_p  = ws + C_OFF;
    float* lp_p = ws + LP_OFF;
    int t0v = t0, nst = ch;
    void* args[] = { (void*)&w_ih, (void*)&w_hh, (void*)&w_out, (void*)&b_out,
                     (void*)&emb_table, (void*)&seq_lens, (void*)&xwbp,
                     (void*)&u_p, (void*)&c_p, (void*)&lp_p, (void*)&out,
                     (void*)&bar, (void*)&bar_base, (void*)&t0v, (void*)&nst };
    hipLaunchCooperativeKernel((void*)k_steps, dim3(256), dim3(512), args, 0, stream);
    bar_base += (unsigned)(2 * ch) * 256u;
  }
}